// Round 18
// baseline (167.844 us; speedup 1.0000x reference)
//
#include <hip/hip_runtime.h>
#include <hip/hip_bf16.h>
#include <cstdint>
#include <cstddef>

#define SCALE_ 0.125f
// B=16 N=256 C=512 H=8 HD=64 E=64

typedef float f4_ __attribute__((ext_vector_type(4)));
typedef __bf16 bf2_ __attribute__((ext_vector_type(2)));
typedef short bf8f_ __attribute__((ext_vector_type(8)));   // MFMA A/B frag (8 bf16)
typedef float f32x4_ __attribute__((ext_vector_type(4)));  // MFMA C/D frag

__device__ __forceinline__ unsigned pk2(float a, float b) {
  union { __hip_bfloat16 h[2]; unsigned u; } x;
  x.h[0] = __float2bfloat16(a);
  x.h[1] = __float2bfloat16(b);
  return x.u;
}
__device__ __forceinline__ unsigned short bf16b(float a) {
  union { __hip_bfloat16 h; unsigned short s; } x;
  x.h = __float2bfloat16(a);
  return x.s;
}
__device__ __forceinline__ float blo(unsigned u) { return __uint_as_float(u << 16); }
__device__ __forceinline__ float bhi(unsigned u) { return __uint_as_float(u & 0xffff0000u); }
__device__ __forceinline__ float b2f(unsigned short s) { return __uint_as_float(((unsigned)s) << 16); }

// packed bf16 pair dot: d = a.lo*b.lo + a.hi*b.hi + c  (one VALU op on gfx950)
__device__ __forceinline__ float dot2b(unsigned a, unsigned b, float c) {
#if __has_builtin(__builtin_amdgcn_fdot2_f32_bf16)
  return __builtin_amdgcn_fdot2_f32_bf16(__builtin_bit_cast(bf2_, a),
                                         __builtin_bit_cast(bf2_, b), c, false);
#else
  return fmaf(blo(a), blo(b), fmaf(bhi(a), bhi(b), c));
#endif
}

template<int CTRL, int RM>
__device__ __forceinline__ float dppadd(float v) {
  int x = __builtin_amdgcn_update_dpp(0, __float_as_int(v), CTRL, RM, 0xf, true);
  return v + __int_as_float(x);
}
__device__ __forceinline__ float wave_sum64(float v) {
  v = dppadd<0x111, 0xf>(v);   // row_shr:1
  v = dppadd<0x112, 0xf>(v);   // row_shr:2
  v = dppadd<0x114, 0xf>(v);   // row_shr:4
  v = dppadd<0x118, 0xf>(v);   // row_shr:8
  v = dppadd<0x142, 0xa>(v);   // row_bcast:15 -> rows 1,3
  v = dppadd<0x143, 0xc>(v);   // row_bcast:31 -> rows 2,3
  return __int_as_float(__builtin_amdgcn_readlane(__float_as_int(v), 63));
}

// ------- Kernel 1: QKV projection GEMM via MFMA (bf16, f32 in, bf16 out) ----
__global__ __launch_bounds__(256) void qkv_gemm(
    const float* __restrict__ X, const float* __restrict__ W,
    unsigned short* __restrict__ qb, uint2* __restrict__ ktq, uint2* __restrict__ vq)
{
  __shared__ alignas(16) unsigned ABbuf[128*36 + 64*36];   // A | B, 27 KB
  unsigned* A_pk = ABbuf;                  // [128 rows][36 uints] (72 bf16)
  unsigned* B_pk = ABbuf + 128*36;         // [64 cols][36 uints]
  unsigned short* A16 = (unsigned short*)A_pk;
  unsigned short* B16 = (unsigned short*)B_pk;
  unsigned short* C16 = (unsigned short*)ABbuf;  // reuse: [128][68] bf16

  const int t  = threadIdx.x;
  const int lane = t & 63;
  const int wv = t >> 6;
  const int m0 = blockIdx.x * 128;
  const int o0 = blockIdx.y * 64;
  const int wrow = wv * 32;

  f32x4_ acc[2][4];
  #pragma unroll
  for (int fm = 0; fm < 2; fm++)
    #pragma unroll
    for (int fn = 0; fn < 4; fn++) acc[fm][fn] = (f32x4_){0.f, 0.f, 0.f, 0.f};

  const float4* X4 = (const float4*)X;
  const float4* W4 = (const float4*)W;

  for (int cc = 0; cc < 512; cc += 64) {
    #pragma unroll
    for (int i = 0; i < 8; i++) {
      int id = t + 256*i;
      int row = id >> 4, c4 = id & 15;
      float4 a = X4[(size_t)(m0 + row)*128 + (cc >> 2) + c4];
      A_pk[row*36 + c4*2    ] = pk2(a.x, a.y);
      A_pk[row*36 + c4*2 + 1] = pk2(a.z, a.w);
    }
    #pragma unroll
    for (int i = 0; i < 4; i++) {
      int id = t + 256*i;
      int row = id >> 4, c4 = id & 15;
      float4 w = W4[(size_t)(o0 + row)*128 + (cc >> 2) + c4];
      B_pk[row*36 + c4*2    ] = pk2(w.x, w.y);
      B_pk[row*36 + c4*2 + 1] = pk2(w.z, w.w);
    }
    __syncthreads();
    #pragma unroll
    for (int ks = 0; ks < 64; ks += 32) {
      const int kb = ks + (lane >> 4)*8;
      bf8f_ af0 = *(const bf8f_*)&A16[(wrow      + (lane & 15))*72 + kb];
      bf8f_ af1 = *(const bf8f_*)&A16[(wrow + 16 + (lane & 15))*72 + kb];
      #pragma unroll
      for (int fn = 0; fn < 4; fn++) {
        bf8f_ bf = *(const bf8f_*)&B16[(fn*16 + (lane & 15))*72 + kb];
        acc[0][fn] = __builtin_amdgcn_mfma_f32_16x16x32_bf16(af0, bf, acc[0][fn], 0, 0, 0);
        acc[1][fn] = __builtin_amdgcn_mfma_f32_16x16x32_bf16(af1, bf, acc[1][fn], 0, 0, 0);
      }
    }
    __syncthreads();
  }

  #pragma unroll
  for (int fm = 0; fm < 2; fm++)
    #pragma unroll
    for (int fn = 0; fn < 4; fn++)
      #pragma unroll
      for (int r = 0; r < 4; r++)
        C16[(wrow + fm*16 + (lane >> 4)*4 + r)*68 + fn*16 + (lane & 15)] =
          bf16b(acc[fm][fn][r]);
  __syncthreads();

  const int tm = (t & 15) * 8;
  const int to = (t >> 4) * 4;
  const int three = o0 >> 9;
  const int h = (o0 >> 6) & 7;
  if (three == 0) {
    #pragma unroll
    for (int i = 0; i < 8; i++) {
      int m = m0 + tm + i;
      int b = m >> 8, n = m & 255;
      uint2 u = *(const uint2*)&C16[(tm + i)*68 + to];
      *(uint2*)&qb[((size_t)(b*8 + h)*256 + n)*64 + to] = u;
    }
  } else if (three == 1) {
    #pragma unroll
    for (int i = 0; i < 8; i++) {
      int m = m0 + tm + i;
      int b = m >> 8, n = m & 255;
      uint2 u = *(const uint2*)&C16[(tm + i)*68 + to];
      ktq[(size_t)(b*8 + h)*4096 + (size_t)(to >> 2)*256 + n] = u;
    }
  } else {
    int m = m0 + tm;
    int b = m >> 8, n0 = m & 255;
    #pragma unroll
    for (int ii = 0; ii < 2; ii++) {
      #pragma unroll
      for (int j = 0; j < 4; j++) {
        unsigned ua = C16[(tm + 4*ii    )*68 + to + j];
        unsigned ub = C16[(tm + 4*ii + 1)*68 + to + j];
        unsigned uc = C16[(tm + 4*ii + 2)*68 + to + j];
        unsigned ud = C16[(tm + 4*ii + 3)*68 + to + j];
        vq[(size_t)(b*8 + h)*4096 + (size_t)((n0 >> 2) + ii)*64 + to + j] =
          make_uint2(ua | (ub << 16), uc | (ud << 16));
      }
    }
  }
}

// -------- Kernel 2: fused attn + edge pipeline (4 rows/block, 256t) ---------
// Round-15 structure + (a) p kept in registers (no exp recompute in 4.5),
// (b) phase-5 e-loop unroll 2 (overlap DPP chains), (c) XCD-swizzled blockIdx
// so all 64 blocks of one batch share one XCD's L2 for K/V.
__global__ __launch_bounds__(256) void fused_attn(
    const unsigned short* __restrict__ qb, const uint2* __restrict__ ktq,
    const uint2* __restrict__ vq,
    const float* __restrict__ edge, const unsigned char* __restrict__ mask,
    const float* __restrict__ rw, const float* __restrict__ rb,
    const float* __restrict__ ew, const float* __restrict__ eb,
    const float* __restrict__ fcw, const float* __restrict__ fcb,
    float* __restrict__ out_edge, unsigned short* __restrict__ tmpb)
{
  __shared__ alignas(16) unsigned q_pk[4][8][32];      // 4 KB packed q (d-pairs)
  __shared__ alignas(16) unsigned char pt_raw[16896];  // p (bf16) then t8 (h-pairs)
  __shared__ alignas(16) unsigned short nacc16[4][512];// 4 KB PV result (bf16)
  __shared__ alignas(16) unsigned rw_pk[32][8];        // 1 KB rw e-pairs [ep][h]
  __shared__ alignas(16) unsigned ew_pk[64][4];        // 1 KB ew h-pairs [e][hp]
  __shared__ alignas(16) float eb_s[64];
  __shared__ alignas(16) float pl2[4][64];             // 1 KB
  __shared__ alignas(16) float inv_s[4][8];            // 1/sum

  unsigned short (*p_sb)[8][264] = (unsigned short (*)[8][264])pt_raw; // [r][h][y]
  unsigned (*t8_pk)[4][264] = (unsigned (*)[4][264])pt_raw;            // [r][hp][y]

  const int t = threadIdx.x;
  const int lane = t & 63;
  const int wv = t >> 6;
  // XCD-aware swizzle (bijective on [0,1024)): b tied to bid&7 so one batch's
  // 64 blocks land on one XCD -> K/V L2 lines filled once, not 8x.
  const int bid = blockIdx.x;
  const int q10 = bid >> 3;
  const int b = 2*(bid & 7) + (q10 >> 6);
  const int x0 = (q10 & 63) * 4;
  const int y = t;

  // ---- phase 1: stage q packed (4 rows), rw/ew pairs, eb, mask
  #pragma unroll
  for (int i = 0; i < 4; i++) {
    int id = t + i*256;                 // 1024 uints
    int r = id >> 8, rest = id & 255;
    int h = rest >> 5, d2 = rest & 31;
    q_pk[r][h][d2] =
      *(const unsigned*)&qb[((size_t)(b*8 + h)*256 + x0 + r)*64 + d2*2];
  }
  { int epx = t >> 3, h = t & 7;
    rw_pk[epx][h] = pk2(rw[h*64 + 2*epx], rw[h*64 + 2*epx + 1]); }
  { int e = t >> 2, hp = t & 3;
    ew_pk[e][hp] = pk2(ew[(size_t)e*8 + 2*hp], ew[(size_t)e*8 + 2*hp + 1]); }
  if (t < 64) eb_s[t] = eb[t];
  float madd[4];
  #pragma unroll
  for (int r = 0; r < 4; r++)
    madd[r] = mask[(size_t)b*65536 + (size_t)(x0 + r)*256 + y] ? -1e30f : 0.f;
  __syncthreads();

  // ---- phase 2 (merged): edge bias stream INTERLEAVED with QK^T
  float acc[4][8];
  #pragma unroll
  for (int h = 0; h < 8; h++) {
    float rv = rb[h];
    #pragma unroll
    for (int r = 0; r < 4; r++) acc[r][h] = rv;
  }
  {
    const float* ep = edge + (size_t)b*(64*65536) + (size_t)x0*256 + y;
    #pragma unroll
    for (int h = 0; h < 8; h++) {
      const uint2* kq = ktq + (size_t)(b*8 + h)*4096 + y;
      float qk[4] = {0.f, 0.f, 0.f, 0.f};
      #pragma unroll
      for (int i = 0; i < 4; i++) {
        const int e2 = h*4 + i;
        // bias step e2: 8 NT HBM loads + 32 dot2
        unsigned vp[4];
        #pragma unroll
        for (int r = 0; r < 4; r++) {
          float a = __builtin_nontemporal_load(ep + (size_t)(2*e2)*65536 + r*256);
          float c = __builtin_nontemporal_load(ep + (size_t)(2*e2+1)*65536 + r*256);
          vp[r] = pk2(a, c);
        }
        uint4 w0 = *(const uint4*)&rw_pk[e2][0];
        uint4 w1 = *(const uint4*)&rw_pk[e2][4];
        unsigned wh[8] = {w0.x,w0.y,w0.z,w0.w,w1.x,w1.y,w1.z,w1.w};
        #pragma unroll
        for (int r = 0; r < 4; r++)
          #pragma unroll
          for (int hh = 0; hh < 8; hh++)
            acc[r][hh] = dot2b(vp[r], wh[hh], acc[r][hh]);
        // QK quarter for this h: d4 = i*4..i*4+3 (L2 loads + 32 dot2)
        #pragma unroll
        for (int dd = 0; dd < 4; dd++) {
          const int d4 = i*4 + dd;
          uint2 k = kq[(size_t)d4*256];
          #pragma unroll
          for (int r = 0; r < 4; r++) {
            uint2 qa = *(const uint2*)&q_pk[r][h][d4*2];
            qk[r] = dot2b(k.x, qa.x, qk[r]);
            qk[r] = dot2b(k.y, qa.y, qk[r]);
          }
        }
      }
      #pragma unroll
      for (int r = 0; r < 4; r++) acc[r][h] += SCALE_ * qk[r];
    }
  }

  // ---- phase 3: p = exp(s + mask) -> registers + bf16 LDS
  float p[4][8];
  #pragma unroll
  for (int r = 0; r < 4; r++)
    #pragma unroll
    for (int h = 0; h < 8; h++) {
      p[r][h] = __expf(acc[r][h] + madd[r]);
      p_sb[r][h][y] = bf16b(p[r][h]);
    }
  __syncthreads();

  // ---- phase 4: PV via dot2; v loads shared across 4 rows
  {
    const int h = t >> 5;
    const int i2 = t & 31;
    const int d0 = i2 * 2;
    const unsigned ONES = 0x3F803F80u;   // bf16 {1.0, 1.0}
    const uint4* vp4 = (const uint4*)(vq + (size_t)(b*8 + h)*4096);
    float a[4][2], ps[4];
    #pragma unroll
    for (int r = 0; r < 4; r++) { a[r][0] = 0.f; a[r][1] = 0.f; ps[r] = 0.f; }
    #pragma unroll 2
    for (int y4 = 0; y4 < 64; y4++) {
      uint4 u = vp4[(size_t)y4*32 + i2];
      #pragma unroll
      for (int r = 0; r < 4; r++) {
        uint2 pp = *(const uint2*)&p_sb[r][h][y4*4];
        a[r][0] = dot2b(pp.x, u.x, a[r][0]); a[r][0] = dot2b(pp.y, u.y, a[r][0]);
        a[r][1] = dot2b(pp.x, u.z, a[r][1]); a[r][1] = dot2b(pp.y, u.w, a[r][1]);
        ps[r] = dot2b(pp.x, ONES, ps[r]);    ps[r] = dot2b(pp.y, ONES, ps[r]);
      }
    }
    #pragma unroll
    for (int r = 0; r < 4; r++) {
      float inv = 1.0f / ps[r];
      *(unsigned*)&nacc16[r][h*64 + d0] = pk2(a[r][0]*inv, a[r][1]*inv);
      if (i2 == 0) inv_s[r][h] = inv;
    }
  }
  __syncthreads();   // p_sb fully consumed; nacc + inv ready

  // ---- phase 4.5: t8 = attn_sm + residual (p from registers, no recompute)
  #pragma unroll
  for (int r = 0; r < 4; r++) {
    float v[8];
    #pragma unroll
    for (int h = 0; h < 8; h++)
      v[h] = p[r][h] * inv_s[r][h] + acc[r][h];
    t8_pk[r][0][y] = pk2(v[0], v[1]);
    t8_pk[r][1][y] = pk2(v[2], v[3]);
    t8_pk[r][2][y] = pk2(v[4], v[5]);
    t8_pk[r][3][y] = pk2(v[6], v[7]);
  }
  __syncthreads();

  // ---- phase 5: expand via dot2 + NT edge_out write + DPP pooling
  {
    const int r = wv;
    const int y0 = lane * 4;
    const int xg = x0 + r;
    uint4 tfq[4];
    #pragma unroll
    for (int hp = 0; hp < 4; hp++) tfq[hp] = *(const uint4*)&t8_pk[r][hp][y0];
    uchar4 mb = *(const uchar4*)&mask[(size_t)b*65536 + (size_t)xg*256 + y0];
    const float md0 = mb.x ? -1e30f : 0.f;
    const float md1 = mb.y ? -1e30f : 0.f;
    const float md2 = mb.z ? -1e30f : 0.f;
    const float md3 = mb.w ? -1e30f : 0.f;
    #pragma unroll 2
    for (int e = 0; e < 64; e++) {
      uint4 w = *(const uint4*)&ew_pk[e][0];
      float ebv = eb_s[e];
      float eo0 = dot2b(tfq[3].x, w.w, dot2b(tfq[2].x, w.z,
                  dot2b(tfq[1].x, w.y, dot2b(tfq[0].x, w.x, ebv))));
      float eo1 = dot2b(tfq[3].y, w.w, dot2b(tfq[2].y, w.z,
                  dot2b(tfq[1].y, w.y, dot2b(tfq[0].y, w.x, ebv))));
      float eo2 = dot2b(tfq[3].z, w.w, dot2b(tfq[2].z, w.z,
                  dot2b(tfq[1].z, w.y, dot2b(tfq[0].z, w.x, ebv))));
      float eo3 = dot2b(tfq[3].w, w.w, dot2b(tfq[2].w, w.z,
                  dot2b(tfq[1].w, w.y, dot2b(tfq[0].w, w.x, ebv))));
      float e0v = __expf(eo0+md0), e1v = __expf(eo1+md1);
      float e2v = __expf(eo2+md2), e3v = __expf(eo3+md3);
      float se  = (e0v + e1v) + (e2v + e3v);
      float swe = (e0v*eo0 + e1v*eo1) + (e2v*eo2 + e3v*eo3);
      se  = wave_sum64(se);
      swe = wave_sum64(swe);
      if (lane == 0) pl2[r][e] = swe / se;
      f4_ ov = {eo0, eo1, eo2, eo3};
      __builtin_nontemporal_store(ov,
        (f4_*)&out_edge[((size_t)(b*64 + e)*256 + xg)*256 + y0]);
    }
  }
  __syncthreads();

  // ---- phase 6: node_tmp = PV + pool @ fc_w^T + fc_b (fw shared x4 rows)
  #pragma unroll
  for (int pass = 0; pass < 2; pass++) {
    int cdx = t + pass*256;
    float bias_c = fcb[cdx];
    float a[4];
    #pragma unroll
    for (int r = 0; r < 4; r++) a[r] = b2f(nacc16[r][cdx]) + bias_c;
    const float4* fw4 = (const float4*)fcw;
    #pragma unroll 4
    for (int e4 = 0; e4 < 16; e4++) {
      float4 f = fw4[(size_t)cdx*16 + e4];
      #pragma unroll
      for (int r = 0; r < 4; r++) {
        float4 pl = *(const float4*)&pl2[r][e4*4];
        a[r] += pl.x*f.x + pl.y*f.y + pl.z*f.z + pl.w*f.w;
      }
    }
    #pragma unroll
    for (int r = 0; r < 4; r++)
      tmpb[((size_t)b*256 + x0 + r)*512 + cdx] = bf16b(a[r]);
  }
}

// ------- Kernel 3: output projection GEMM via MFMA (bf16 in, f32 out) -------
__global__ __launch_bounds__(256) void proj_gemm(
    const unsigned short* __restrict__ Xb, const float* __restrict__ W,
    const float* __restrict__ bias, float* __restrict__ out)
{
  __shared__ alignas(16) unsigned ABbuf[128*36 + 64*36];   // A | B, 27 KB
  unsigned* A_pk = ABbuf;
  unsigned* B_pk = ABbuf + 128*36;
  unsigned short* A16 = (unsigned short*)A_pk;
  unsigned short* B16 = (unsigned short*)B_pk;

  const int t  = threadIdx.x;
  const int lane = t & 63;
  const int wv = t >> 6;
  const int m0 = blockIdx.x * 128;
  const int o0 = blockIdx.y * 64;
  const int wrow = wv * 32;

  f32x4_ acc[2][4];
  #pragma unroll
  for (int fm = 0; fm < 2; fm++)
    #pragma unroll
    for (int fn = 0; fn < 4; fn++) acc[fm][fn] = (f32x4_){0.f, 0.f, 0.f, 0.f};

  const uint4* X4 = (const uint4*)Xb;    // row = 64 uint4 (512 bf16)
  const float4* W4 = (const float4*)W;

  for (int cc = 0; cc < 512; cc += 64) {
    // stage A (already bf16): 128 rows x 8 uint4 per row
    #pragma unroll
    for (int i = 0; i < 4; i++) {
      int id = t + 256*i;
      int row = id >> 3, c8 = id & 7;
      uint4 a = X4[(size_t)(m0 + row)*64 + (cc >> 3) + c8];
      A_pk[row*36 + c8*4    ] = a.x;
      A_pk[row*36 + c8*4 + 1] = a.y;
      A_pk[row*36 + c8*4 + 2] = a.z;
      A_pk[row*36 + c8*4 + 3] = a.w;
    }
    // stage B (f32 -> packed bf16): 64 rows x 16 float4
    #pragma unroll
    for (int i = 0; i < 4; i++) {
      int id = t + 256*i;
      int row = id >> 4, c4 = id & 15;
      float4 w = W4[(size_t)(o0 + row)*128 + (cc >> 2) + c4];
      B_pk[row*36 + c4*2    ] = pk2(w.x, w.y);
      B_pk[row*36 + c4*2 + 1] = pk2(w.z, w.w);
    }
    __syncthreads();
    #pragma unroll
    for (int ks = 0; ks < 64; ks += 32) {
      const int kb = ks + (lane >> 4)*8;
      bf8f_ af0 = *(const bf8f_*)&A16[(wrow      + (lane & 15))*72 + kb];
      bf8f_ af1 = *(const bf8f_*)&A16[(wrow + 16 + (lane & 15))*72 + kb];
      #pragma unroll
      for (int fn = 0; fn < 4; fn++) {
        bf8f_ bf = *(const bf8f_*)&B16[(fn*16 + (lane & 15))*72 + kb];
        acc[0][fn] = __builtin_amdgcn_mfma_f32_16x16x32_bf16(af0, bf, acc[0][fn], 0, 0, 0);
        acc[1][fn] = __builtin_amdgcn_mfma_f32_16x16x32_bf16(af1, bf, acc[1][fn], 0, 0, 0);
      }
    }
    __syncthreads();
  }

  // epilogue: direct store from C frag layout (col=lane&15, row=(lane>>4)*4+r)
  #pragma unroll
  for (int fn = 0; fn < 4; fn++) {
    const int col = o0 + fn*16 + (lane & 15);
    const float bb = bias[col];
    #pragma unroll
    for (int fm = 0; fm < 2; fm++) {
      #pragma unroll
      for (int r = 0; r < 4; r++) {
        int m = m0 + wrow + fm*16 + (lane >> 4)*4 + r;
        out[(size_t)m*512 + col] = acc[fm][fn][r] + bb;
      }
    }
  }
}

extern "C" void kernel_launch(void* const* d_in, const int* in_sizes, int n_in,
                              void* d_out, int out_size, void* d_ws, size_t ws_size,
                              hipStream_t stream)
{
  (void)in_sizes; (void)n_in; (void)out_size; (void)ws_size;
  const float* node   = (const float*)d_in[0];
  const float* edge   = (const float*)d_in[1];
  const unsigned char* mask = (const unsigned char*)d_in[2];
  const float* qkv_w  = (const float*)d_in[3];
  const float* proj_w = (const float*)d_in[4];
  const float* proj_b = (const float*)d_in[5];
  const float* rw     = (const float*)d_in[6];
  const float* rb     = (const float*)d_in[7];
  const float* ew     = (const float*)d_in[8];
  const float* eb     = (const float*)d_in[9];
  const float* fcw    = (const float*)d_in[10];
  const float* fcb    = (const float*)d_in[11];

  float* out_node = (float*)d_out;
  float* out_edge = out_node + (size_t)16*256*512;

  char* ws = (char*)d_ws;
  unsigned short* qb  = (unsigned short*)(ws);                    // 4 MB
  uint2*          ktq = (uint2*)         (ws + (size_t)4*1024*1024);
  uint2*          vq  = (uint2*)         (ws + (size_t)8*1024*1024);
  unsigned short* tmpb= (unsigned short*)(ws + (size_t)12*1024*1024);

  qkv_gemm <<<dim3(32, 24, 1), 256, 0, stream>>>(node, qkv_w, qb, ktq, vq);
  fused_attn<<<dim3(1024, 1, 1), 256, 0, stream>>>(qb, ktq, vq, edge, mask,
                                                   rw, rb, ew, eb, fcw, fcb,
                                                   out_edge, tmpb);
  proj_gemm<<<dim3(32, 8, 1), 256, 0, stream>>>(tmpb, proj_w, proj_b, out_node);
}

// Round 19
// 162.217 us; speedup vs baseline: 1.0347x; 1.0347x over previous
//
#include <hip/hip_runtime.h>
#include <hip/hip_bf16.h>
#include <cstdint>
#include <cstddef>

#define SCALE_ 0.125f
// B=16 N=256 C=512 H=8 HD=64 E=64

typedef float f4_ __attribute__((ext_vector_type(4)));
typedef __bf16 bf2_ __attribute__((ext_vector_type(2)));
typedef short bf8f_ __attribute__((ext_vector_type(8)));   // MFMA A/B frag (8 bf16)
typedef float f32x4_ __attribute__((ext_vector_type(4)));  // MFMA C/D frag

__device__ __forceinline__ unsigned pk2(float a, float b) {
  union { __hip_bfloat16 h[2]; unsigned u; } x;
  x.h[0] = __float2bfloat16(a);
  x.h[1] = __float2bfloat16(b);
  return x.u;
}
__device__ __forceinline__ unsigned short bf16b(float a) {
  union { __hip_bfloat16 h; unsigned short s; } x;
  x.h = __float2bfloat16(a);
  return x.s;
}
__device__ __forceinline__ float blo(unsigned u) { return __uint_as_float(u << 16); }
__device__ __forceinline__ float bhi(unsigned u) { return __uint_as_float(u & 0xffff0000u); }
__device__ __forceinline__ float b2f(unsigned short s) { return __uint_as_float(((unsigned)s) << 16); }

// packed bf16 pair dot: d = a.lo*b.lo + a.hi*b.hi + c  (one VALU op on gfx950)
__device__ __forceinline__ float dot2b(unsigned a, unsigned b, float c) {
#if __has_builtin(__builtin_amdgcn_fdot2_f32_bf16)
  return __builtin_amdgcn_fdot2_f32_bf16(__builtin_bit_cast(bf2_, a),
                                         __builtin_bit_cast(bf2_, b), c, false);
#else
  return fmaf(blo(a), blo(b), fmaf(bhi(a), bhi(b), c));
#endif
}

template<int CTRL, int RM>
__device__ __forceinline__ float dppadd(float v) {
  int x = __builtin_amdgcn_update_dpp(0, __float_as_int(v), CTRL, RM, 0xf, true);
  return v + __int_as_float(x);
}
__device__ __forceinline__ float wave_sum64(float v) {
  v = dppadd<0x111, 0xf>(v);   // row_shr:1
  v = dppadd<0x112, 0xf>(v);   // row_shr:2
  v = dppadd<0x114, 0xf>(v);   // row_shr:4
  v = dppadd<0x118, 0xf>(v);   // row_shr:8
  v = dppadd<0x142, 0xa>(v);   // row_bcast:15 -> rows 1,3
  v = dppadd<0x143, 0xc>(v);   // row_bcast:31 -> rows 2,3
  return __int_as_float(__builtin_amdgcn_readlane(__float_as_int(v), 63));
}

// ------- Kernel 1: QKV projection GEMM via MFMA (bf16, f32 in, bf16 out) ----
__global__ __launch_bounds__(256) void qkv_gemm(
    const float* __restrict__ X, const float* __restrict__ W,
    unsigned short* __restrict__ qb, uint2* __restrict__ ktq, uint2* __restrict__ vq)
{
  __shared__ alignas(16) unsigned ABbuf[128*36 + 64*36];   // A | B, 27 KB
  unsigned* A_pk = ABbuf;                  // [128 rows][36 uints] (72 bf16)
  unsigned* B_pk = ABbuf + 128*36;         // [64 cols][36 uints]
  unsigned short* A16 = (unsigned short*)A_pk;
  unsigned short* B16 = (unsigned short*)B_pk;
  unsigned short* C16 = (unsigned short*)ABbuf;  // reuse: [128][68] bf16

  const int t  = threadIdx.x;
  const int lane = t & 63;
  const int wv = t >> 6;
  const int m0 = blockIdx.x * 128;
  const int o0 = blockIdx.y * 64;
  const int wrow = wv * 32;

  f32x4_ acc[2][4];
  #pragma unroll
  for (int fm = 0; fm < 2; fm++)
    #pragma unroll
    for (int fn = 0; fn < 4; fn++) acc[fm][fn] = (f32x4_){0.f, 0.f, 0.f, 0.f};

  const float4* X4 = (const float4*)X;
  const float4* W4 = (const float4*)W;

  for (int cc = 0; cc < 512; cc += 64) {
    #pragma unroll
    for (int i = 0; i < 8; i++) {
      int id = t + 256*i;
      int row = id >> 4, c4 = id & 15;
      float4 a = X4[(size_t)(m0 + row)*128 + (cc >> 2) + c4];
      A_pk[row*36 + c4*2    ] = pk2(a.x, a.y);
      A_pk[row*36 + c4*2 + 1] = pk2(a.z, a.w);
    }
    #pragma unroll
    for (int i = 0; i < 4; i++) {
      int id = t + 256*i;
      int row = id >> 4, c4 = id & 15;
      float4 w = W4[(size_t)(o0 + row)*128 + (cc >> 2) + c4];
      B_pk[row*36 + c4*2    ] = pk2(w.x, w.y);
      B_pk[row*36 + c4*2 + 1] = pk2(w.z, w.w);
    }
    __syncthreads();
    #pragma unroll
    for (int ks = 0; ks < 64; ks += 32) {
      const int kb = ks + (lane >> 4)*8;
      bf8f_ af0 = *(const bf8f_*)&A16[(wrow      + (lane & 15))*72 + kb];
      bf8f_ af1 = *(const bf8f_*)&A16[(wrow + 16 + (lane & 15))*72 + kb];
      #pragma unroll
      for (int fn = 0; fn < 4; fn++) {
        bf8f_ bf = *(const bf8f_*)&B16[(fn*16 + (lane & 15))*72 + kb];
        acc[0][fn] = __builtin_amdgcn_mfma_f32_16x16x32_bf16(af0, bf, acc[0][fn], 0, 0, 0);
        acc[1][fn] = __builtin_amdgcn_mfma_f32_16x16x32_bf16(af1, bf, acc[1][fn], 0, 0, 0);
      }
    }
    __syncthreads();
  }

  #pragma unroll
  for (int fm = 0; fm < 2; fm++)
    #pragma unroll
    for (int fn = 0; fn < 4; fn++)
      #pragma unroll
      for (int r = 0; r < 4; r++)
        C16[(wrow + fm*16 + (lane >> 4)*4 + r)*68 + fn*16 + (lane & 15)] =
          bf16b(acc[fm][fn][r]);
  __syncthreads();

  const int tm = (t & 15) * 8;
  const int to = (t >> 4) * 4;
  const int three = o0 >> 9;
  const int h = (o0 >> 6) & 7;
  if (three == 0) {
    #pragma unroll
    for (int i = 0; i < 8; i++) {
      int m = m0 + tm + i;
      int b = m >> 8, n = m & 255;
      uint2 u = *(const uint2*)&C16[(tm + i)*68 + to];
      *(uint2*)&qb[((size_t)(b*8 + h)*256 + n)*64 + to] = u;
    }
  } else if (three == 1) {
    #pragma unroll
    for (int i = 0; i < 8; i++) {
      int m = m0 + tm + i;
      int b = m >> 8, n = m & 255;
      uint2 u = *(const uint2*)&C16[(tm + i)*68 + to];
      ktq[(size_t)(b*8 + h)*4096 + (size_t)(to >> 2)*256 + n] = u;
    }
  } else {
    int m = m0 + tm;
    int b = m >> 8, n0 = m & 255;
    #pragma unroll
    for (int ii = 0; ii < 2; ii++) {
      #pragma unroll
      for (int j = 0; j < 4; j++) {
        unsigned ua = C16[(tm + 4*ii    )*68 + to + j];
        unsigned ub = C16[(tm + 4*ii + 1)*68 + to + j];
        unsigned uc = C16[(tm + 4*ii + 2)*68 + to + j];
        unsigned ud = C16[(tm + 4*ii + 3)*68 + to + j];
        vq[(size_t)(b*8 + h)*4096 + (size_t)((n0 >> 2) + ii)*64 + to + j] =
          make_uint2(ua | (ub << 16), uc | (ud << 16));
      }
    }
  }
}

// -------- Kernel 2: fused attn + edge pipeline (4 rows/block, 256t) ---------
// Round-15-benched version (best measured in round-17 combo: 162.4 µs total):
// merged phase 2 with scalar NT edge loads interleaved with QK^T.
__global__ __launch_bounds__(256) void fused_attn(
    const unsigned short* __restrict__ qb, const uint2* __restrict__ ktq,
    const uint2* __restrict__ vq,
    const float* __restrict__ edge, const unsigned char* __restrict__ mask,
    const float* __restrict__ rw, const float* __restrict__ rb,
    const float* __restrict__ ew, const float* __restrict__ eb,
    const float* __restrict__ fcw, const float* __restrict__ fcb,
    float* __restrict__ out_edge, unsigned short* __restrict__ tmpb)
{
  __shared__ alignas(16) unsigned q_pk[4][8][32];      // 4 KB packed q (d-pairs)
  __shared__ alignas(16) unsigned char pt_raw[16896];  // p (bf16) then t8 (h-pairs)
  __shared__ alignas(16) unsigned short nacc16[4][512];// 4 KB PV result (bf16)
  __shared__ alignas(16) unsigned rw_pk[32][8];        // 1 KB rw e-pairs [ep][h]
  __shared__ alignas(16) unsigned ew_pk[64][4];        // 1 KB ew h-pairs [e][hp]
  __shared__ alignas(16) float eb_s[64];
  __shared__ alignas(16) float pl2[4][64];             // 1 KB
  __shared__ alignas(16) float inv_s[4][8];            // 1/sum

  unsigned short (*p_sb)[8][264] = (unsigned short (*)[8][264])pt_raw; // [r][h][y]
  unsigned (*t8_pk)[4][264] = (unsigned (*)[4][264])pt_raw;            // [r][hp][y]

  const int t = threadIdx.x;
  const int lane = t & 63;
  const int wv = t >> 6;
  const int b = blockIdx.x >> 6;
  const int x0 = (blockIdx.x & 63) * 4;
  const int y = t;

  // ---- phase 1: stage q packed (4 rows), rw/ew pairs, eb, mask
  #pragma unroll
  for (int i = 0; i < 4; i++) {
    int id = t + i*256;                 // 1024 uints
    int r = id >> 8, rest = id & 255;
    int h = rest >> 5, d2 = rest & 31;
    q_pk[r][h][d2] =
      *(const unsigned*)&qb[((size_t)(b*8 + h)*256 + x0 + r)*64 + d2*2];
  }
  { int epx = t >> 3, h = t & 7;
    rw_pk[epx][h] = pk2(rw[h*64 + 2*epx], rw[h*64 + 2*epx + 1]); }
  { int e = t >> 2, hp = t & 3;
    ew_pk[e][hp] = pk2(ew[(size_t)e*8 + 2*hp], ew[(size_t)e*8 + 2*hp + 1]); }
  if (t < 64) eb_s[t] = eb[t];
  float madd[4];
  #pragma unroll
  for (int r = 0; r < 4; r++)
    madd[r] = mask[(size_t)b*65536 + (size_t)(x0 + r)*256 + y] ? -1e30f : 0.f;
  __syncthreads();

  // ---- phase 2 (merged): edge bias stream INTERLEAVED with QK^T
  float acc[4][8];
  #pragma unroll
  for (int h = 0; h < 8; h++) {
    float rv = rb[h];
    #pragma unroll
    for (int r = 0; r < 4; r++) acc[r][h] = rv;
  }
  {
    const float* ep = edge + (size_t)b*(64*65536) + (size_t)x0*256 + y;
    #pragma unroll
    for (int h = 0; h < 8; h++) {
      const uint2* kq = ktq + (size_t)(b*8 + h)*4096 + y;
      float qk[4] = {0.f, 0.f, 0.f, 0.f};
      #pragma unroll
      for (int i = 0; i < 4; i++) {
        const int e2 = h*4 + i;
        // bias step e2: 8 NT HBM loads + 32 dot2
        unsigned vp[4];
        #pragma unroll
        for (int r = 0; r < 4; r++) {
          float a = __builtin_nontemporal_load(ep + (size_t)(2*e2)*65536 + r*256);
          float c = __builtin_nontemporal_load(ep + (size_t)(2*e2+1)*65536 + r*256);
          vp[r] = pk2(a, c);
        }
        uint4 w0 = *(const uint4*)&rw_pk[e2][0];
        uint4 w1 = *(const uint4*)&rw_pk[e2][4];
        unsigned wh[8] = {w0.x,w0.y,w0.z,w0.w,w1.x,w1.y,w1.z,w1.w};
        #pragma unroll
        for (int r = 0; r < 4; r++)
          #pragma unroll
          for (int hh = 0; hh < 8; hh++)
            acc[r][hh] = dot2b(vp[r], wh[hh], acc[r][hh]);
        // QK quarter for this h: d4 = i*4..i*4+3 (L2 loads + 32 dot2)
        #pragma unroll
        for (int dd = 0; dd < 4; dd++) {
          const int d4 = i*4 + dd;
          uint2 k = kq[(size_t)d4*256];
          #pragma unroll
          for (int r = 0; r < 4; r++) {
            uint2 qa = *(const uint2*)&q_pk[r][h][d4*2];
            qk[r] = dot2b(k.x, qa.x, qk[r]);
            qk[r] = dot2b(k.y, qa.y, qk[r]);
          }
        }
      }
      #pragma unroll
      for (int r = 0; r < 4; r++) acc[r][h] += SCALE_ * qk[r];
    }
  }

  // ---- phase 3: p = exp(s + mask) -> bf16 LDS
  #pragma unroll
  for (int r = 0; r < 4; r++)
    #pragma unroll
    for (int h = 0; h < 8; h++)
      p_sb[r][h][y] = bf16b(__expf(acc[r][h] + madd[r]));
  __syncthreads();

  // ---- phase 4: PV via dot2; v loads shared across 4 rows
  {
    const int h = t >> 5;
    const int i2 = t & 31;
    const int d0 = i2 * 2;
    const unsigned ONES = 0x3F803F80u;   // bf16 {1.0, 1.0}
    const uint4* vp4 = (const uint4*)(vq + (size_t)(b*8 + h)*4096);
    float a[4][2], ps[4];
    #pragma unroll
    for (int r = 0; r < 4; r++) { a[r][0] = 0.f; a[r][1] = 0.f; ps[r] = 0.f; }
    #pragma unroll 2
    for (int y4 = 0; y4 < 64; y4++) {
      uint4 u = vp4[(size_t)y4*32 + i2];
      #pragma unroll
      for (int r = 0; r < 4; r++) {
        uint2 pp = *(const uint2*)&p_sb[r][h][y4*4];
        a[r][0] = dot2b(pp.x, u.x, a[r][0]); a[r][0] = dot2b(pp.y, u.y, a[r][0]);
        a[r][1] = dot2b(pp.x, u.z, a[r][1]); a[r][1] = dot2b(pp.y, u.w, a[r][1]);
        ps[r] = dot2b(pp.x, ONES, ps[r]);    ps[r] = dot2b(pp.y, ONES, ps[r]);
      }
    }
    #pragma unroll
    for (int r = 0; r < 4; r++) {
      float inv = 1.0f / ps[r];
      *(unsigned*)&nacc16[r][h*64 + d0] = pk2(a[r][0]*inv, a[r][1]*inv);
      if (i2 == 0) inv_s[r][h] = inv;
    }
  }
  __syncthreads();   // p_sb fully consumed; nacc + inv ready

  // ---- phase 4.5: t8 = attn_sm + residual -> packed h-pairs (aliases p_sb)
  #pragma unroll
  for (int r = 0; r < 4; r++) {
    float v[8];
    #pragma unroll
    for (int h = 0; h < 8; h++)
      v[h] = __expf(acc[r][h] + madd[r]) * inv_s[r][h] + acc[r][h];
    t8_pk[r][0][y] = pk2(v[0], v[1]);
    t8_pk[r][1][y] = pk2(v[2], v[3]);
    t8_pk[r][2][y] = pk2(v[4], v[5]);
    t8_pk[r][3][y] = pk2(v[6], v[7]);
  }
  __syncthreads();

  // ---- phase 5: expand via dot2 + NT edge_out write + DPP pooling
  {
    const int r = wv;
    const int y0 = lane * 4;
    const int xg = x0 + r;
    uint4 tfq[4];
    #pragma unroll
    for (int hp = 0; hp < 4; hp++) tfq[hp] = *(const uint4*)&t8_pk[r][hp][y0];
    uchar4 mb = *(const uchar4*)&mask[(size_t)b*65536 + (size_t)xg*256 + y0];
    const float md0 = mb.x ? -1e30f : 0.f;
    const float md1 = mb.y ? -1e30f : 0.f;
    const float md2 = mb.z ? -1e30f : 0.f;
    const float md3 = mb.w ? -1e30f : 0.f;
    for (int e = 0; e < 64; e++) {
      uint4 w = *(const uint4*)&ew_pk[e][0];
      float ebv = eb_s[e];
      float eo0 = dot2b(tfq[3].x, w.w, dot2b(tfq[2].x, w.z,
                  dot2b(tfq[1].x, w.y, dot2b(tfq[0].x, w.x, ebv))));
      float eo1 = dot2b(tfq[3].y, w.w, dot2b(tfq[2].y, w.z,
                  dot2b(tfq[1].y, w.y, dot2b(tfq[0].y, w.x, ebv))));
      float eo2 = dot2b(tfq[3].z, w.w, dot2b(tfq[2].z, w.z,
                  dot2b(tfq[1].z, w.y, dot2b(tfq[0].z, w.x, ebv))));
      float eo3 = dot2b(tfq[3].w, w.w, dot2b(tfq[2].w, w.z,
                  dot2b(tfq[1].w, w.y, dot2b(tfq[0].w, w.x, ebv))));
      float e0v = __expf(eo0+md0), e1v = __expf(eo1+md1);
      float e2v = __expf(eo2+md2), e3v = __expf(eo3+md3);
      float se  = (e0v + e1v) + (e2v + e3v);
      float swe = (e0v*eo0 + e1v*eo1) + (e2v*eo2 + e3v*eo3);
      se  = wave_sum64(se);
      swe = wave_sum64(swe);
      if (lane == 0) pl2[r][e] = swe / se;
      f4_ ov = {eo0, eo1, eo2, eo3};
      __builtin_nontemporal_store(ov,
        (f4_*)&out_edge[((size_t)(b*64 + e)*256 + xg)*256 + y0]);
    }
  }
  __syncthreads();

  // ---- phase 6: node_tmp = PV + pool @ fc_w^T + fc_b (fw shared x4 rows)
  #pragma unroll
  for (int pass = 0; pass < 2; pass++) {
    int cdx = t + pass*256;
    float bias_c = fcb[cdx];
    float a[4];
    #pragma unroll
    for (int r = 0; r < 4; r++) a[r] = b2f(nacc16[r][cdx]) + bias_c;
    const float4* fw4 = (const float4*)fcw;
    #pragma unroll 4
    for (int e4 = 0; e4 < 16; e4++) {
      float4 f = fw4[(size_t)cdx*16 + e4];
      #pragma unroll
      for (int r = 0; r < 4; r++) {
        float4 pl = *(const float4*)&pl2[r][e4*4];
        a[r] += pl.x*f.x + pl.y*f.y + pl.z*f.z + pl.w*f.w;
      }
    }
    #pragma unroll
    for (int r = 0; r < 4; r++)
      tmpb[((size_t)b*256 + x0 + r)*512 + cdx] = bf16b(a[r]);
  }
}

// ------- Kernel 3: output projection GEMM via MFMA (bf16 in, f32 out) -------
__global__ __launch_bounds__(256) void proj_gemm(
    const unsigned short* __restrict__ Xb, const float* __restrict__ W,
    const float* __restrict__ bias, float* __restrict__ out)
{
  __shared__ alignas(16) unsigned ABbuf[128*36 + 64*36];   // A | B, 27 KB
  unsigned* A_pk = ABbuf;
  unsigned* B_pk = ABbuf + 128*36;
  unsigned short* A16 = (unsigned short*)A_pk;
  unsigned short* B16 = (unsigned short*)B_pk;

  const int t  = threadIdx.x;
  const int lane = t & 63;
  const int wv = t >> 6;
  const int m0 = blockIdx.x * 128;
  const int o0 = blockIdx.y * 64;
  const int wrow = wv * 32;

  f32x4_ acc[2][4];
  #pragma unroll
  for (int fm = 0; fm < 2; fm++)
    #pragma unroll
    for (int fn = 0; fn < 4; fn++) acc[fm][fn] = (f32x4_){0.f, 0.f, 0.f, 0.f};

  const uint4* X4 = (const uint4*)Xb;    // row = 64 uint4 (512 bf16)
  const float4* W4 = (const float4*)W;

  for (int cc = 0; cc < 512; cc += 64) {
    // stage A (already bf16): 128 rows x 8 uint4 per row
    #pragma unroll
    for (int i = 0; i < 4; i++) {
      int id = t + 256*i;
      int row = id >> 3, c8 = id & 7;
      uint4 a = X4[(size_t)(m0 + row)*64 + (cc >> 3) + c8];
      A_pk[row*36 + c8*4    ] = a.x;
      A_pk[row*36 + c8*4 + 1] = a.y;
      A_pk[row*36 + c8*4 + 2] = a.z;
      A_pk[row*36 + c8*4 + 3] = a.w;
    }
    // stage B (f32 -> packed bf16): 64 rows x 16 float4
    #pragma unroll
    for (int i = 0; i < 4; i++) {
      int id = t + 256*i;
      int row = id >> 4, c4 = id & 15;
      float4 w = W4[(size_t)(o0 + row)*128 + (cc >> 2) + c4];
      B_pk[row*36 + c4*2    ] = pk2(w.x, w.y);
      B_pk[row*36 + c4*2 + 1] = pk2(w.z, w.w);
    }
    __syncthreads();
    #pragma unroll
    for (int ks = 0; ks < 64; ks += 32) {
      const int kb = ks + (lane >> 4)*8;
      bf8f_ af0 = *(const bf8f_*)&A16[(wrow      + (lane & 15))*72 + kb];
      bf8f_ af1 = *(const bf8f_*)&A16[(wrow + 16 + (lane & 15))*72 + kb];
      #pragma unroll
      for (int fn = 0; fn < 4; fn++) {
        bf8f_ bf = *(const bf8f_*)&B16[(fn*16 + (lane & 15))*72 + kb];
        acc[0][fn] = __builtin_amdgcn_mfma_f32_16x16x32_bf16(af0, bf, acc[0][fn], 0, 0, 0);
        acc[1][fn] = __builtin_amdgcn_mfma_f32_16x16x32_bf16(af1, bf, acc[1][fn], 0, 0, 0);
      }
    }
    __syncthreads();
  }

  // epilogue: direct store from C frag layout (col=lane&15, row=(lane>>4)*4+r)
  #pragma unroll
  for (int fn = 0; fn < 4; fn++) {
    const int col = o0 + fn*16 + (lane & 15);
    const float bb = bias[col];
    #pragma unroll
    for (int fm = 0; fm < 2; fm++) {
      #pragma unroll
      for (int r = 0; r < 4; r++) {
        int m = m0 + wrow + fm*16 + (lane >> 4)*4 + r;
        out[(size_t)m*512 + col] = acc[fm][fn][r] + bb;
      }
    }
  }
}

extern "C" void kernel_launch(void* const* d_in, const int* in_sizes, int n_in,
                              void* d_out, int out_size, void* d_ws, size_t ws_size,
                              hipStream_t stream)
{
  (void)in_sizes; (void)n_in; (void)out_size; (void)ws_size;
  const float* node   = (const float*)d_in[0];
  const float* edge   = (const float*)d_in[1];
  const unsigned char* mask = (const unsigned char*)d_in[2];
  const float* qkv_w  = (const float*)d_in[3];
  const float* proj_w = (const float*)d_in[4];
  const float* proj_b = (const float*)d_in[5];
  const float* rw     = (const float*)d_in[6];
  const float* rb     = (const float*)d_in[7];
  const float* ew     = (const float*)d_in[8];
  const float* eb     = (const float*)d_in[9];
  const float* fcw    = (const float*)d_in[10];
  const float* fcb    = (const float*)d_in[11];

  float* out_node = (float*)d_out;
  float* out_edge = out_node + (size_t)16*256*512;

  char* ws = (char*)d_ws;
  unsigned short* qb  = (unsigned short*)(ws);                    // 4 MB
  uint2*          ktq = (uint2*)         (ws + (size_t)4*1024*1024);
  uint2*          vq  = (uint2*)         (ws + (size_t)8*1024*1024);
  unsigned short* tmpb= (unsigned short*)(ws + (size_t)12*1024*1024);

  qkv_gemm <<<dim3(32, 24, 1), 256, 0, stream>>>(node, qkv_w, qb, ktq, vq);
  fused_attn<<<dim3(1024, 1, 1), 256, 0, stream>>>(qb, ktq, vq, edge, mask,
                                                   rw, rb, ew, eb, fcw, fcb,
                                                   out_edge, tmpb);
  proj_gemm<<<dim3(32, 8, 1), 256, 0, stream>>>(tmpb, proj_w, proj_b, out_node);
}